// Round 6
// baseline (240.683 us; speedup 1.0000x reference)
//
#include <hip/hip_runtime.h>

// B=4, N=2048, C=256, ic=128.  Algebra (validated rounds 1-8):
//   T=lin(aim,theta) P=lin(detect,phi) Gd=lin(detect,g) Ga=lin(aim,g2)   [bf16]
//   X_v := per-batch view [128,4096] of [2048,256] (pure reshape)
//   S_aT = Gd_v @ P_v^T ; S_bT = Ga_v @ T_v^T        [128,128] fp32
//   out_aim[r,d] = (1/4096)*sum_k S_aT[r/16,k]*TW[16k+(r%16),d] + Wb[d] + aim[r,d]
//   with TW = T @ W^T  (and symmetrically out_det from S_bT, PQ = P @ Q^T).
// Round 9: occupancy 2 -> 4 blocks/CU. Round-8 ran 120 us with Occupancy 22%
//   (= 8 waves/CU), MfmaUtil 2.7%: latency-bound, nothing co-resident to hide
//   staging stalls. Now 1024 blocks x 256 thr, __launch_bounds__(256,4)
//   (VGPR<=128 forced, LDS 23KB x4 = 92KB/CU) => capacity exactly 1024,
//   barrier deadlock-free. All phases re-split into 1024 uniform jobs.
//   Barrier: per-block flags + 8 replicated release words (128 pollers each).

typedef __attribute__((ext_vector_type(4))) float  f32x4;
typedef __attribute__((ext_vector_type(8))) __bf16 bf16x8;
typedef __attribute__((ext_vector_type(8))) unsigned short u16x8;
typedef __attribute__((ext_vector_type(4))) unsigned short u16x4;

__device__ inline unsigned short f2bf(float f) {
    union { float f; unsigned u; } c; c.f = f;
    unsigned r = c.u + 0x7FFF + ((c.u >> 16) & 1);   // RNE
    return (unsigned short)(r >> 16);
}
__device__ inline bf16x8 ldfrag(const unsigned short* p) {
    return __builtin_bit_cast(bf16x8, *(const u16x8*)p);
}

#define NBLK 1024

// Contention-free grid barrier, region = 1536 uints per barrier:
//   [0..1023]          per-block arrival flags (write-once)
//   [1024 + 32*i] i<8  replicated release words (each polled by ~128 blocks)
// All 1024 blocks co-resident (grid == 4/CU capacity) => no deadlock.
__device__ inline void gridbar(unsigned* b) {
    __syncthreads();
    const int tid = threadIdx.x;
    if (blockIdx.x == 0) {
        #pragma unroll
        for (int j = 0; j < 4; ++j) {
            int idx = tid + j * 256;
            if (idx > 0) {
                while (__hip_atomic_load(b + idx, __ATOMIC_RELAXED, __HIP_MEMORY_SCOPE_AGENT) == 0)
                    __builtin_amdgcn_s_sleep(8);
            }
        }
        __syncthreads();
        if (tid == 0) {
            __threadfence();               // release own writes; (others fenced before flagging)
            #pragma unroll
            for (int i = 0; i < 8; ++i)
                __hip_atomic_store(b + 1024 + 32 * i, 1u, __ATOMIC_RELAXED, __HIP_MEMORY_SCOPE_AGENT);
        }
        __syncthreads();
    } else {
        if (tid == 0) {
            __threadfence();               // release this block's phase writes
            __hip_atomic_store(b + blockIdx.x, 1u, __ATOMIC_RELAXED, __HIP_MEMORY_SCOPE_AGENT);
            unsigned* rel = b + 1024 + 32 * (blockIdx.x & 7);
            while (__hip_atomic_load(rel, __ATOMIC_RELAXED, __HIP_MEMORY_SCOPE_AGENT) == 0)
                __builtin_amdgcn_s_sleep(8);
            __threadfence();               // acquire
        }
        __syncthreads();
    }
}

struct MegaArgs {
    const float *detect, *aim;
    const float *g_w, *g2_w, *th_w, *ph_w, *W_w, *Q_w;
    const float *b_g, *b_g2, *b_th, *b_ph, *b_W, *b_Q;
    unsigned short *T, *P, *Gd, *Ga, *TW, *PQ;
    float *S;                 // [2][4][128][128] fp32, atomically accumulated
    float *out_aim, *out_det;
    unsigned *bar;            // 2 x 1536 uints
};

__global__ __launch_bounds__(256, 4)
void mega_kernel(MegaArgs a)
{
    // 23040 B max (P1). P2a 10240, P2b 13824, P4 18432.
    __shared__ unsigned short lds[11520];

    const int bid = blockIdx.x, tid = threadIdx.x;
    const int lane = tid & 63, w = tid >> 6;
    const int wr = w >> 1, wc = w & 1, q = lane >> 4, ln = lane & 15;

    // ===== P1: four input linears (fp32 in, inline convert). 1024 jobs ======
    // mat = bid>>8 (0:T th/aim, 1:Ga g2/aim, 2:P ph/det, 3:Gd g/det), mtile 32 rows.
    {
        const int mat = bid >> 8, mtile = bid & 255, m0 = mtile * 32;
        const float* Ap = (mat < 2) ? a.aim : a.detect;
        const float* Wm = mat == 0 ? a.th_w : mat == 1 ? a.g2_w : mat == 2 ? a.ph_w : a.g_w;
        const float* Bv = mat == 0 ? a.b_th : mat == 1 ? a.b_g2 : mat == 2 ? a.b_ph : a.b_g;
        unsigned short* O = mat == 0 ? a.T : mat == 1 ? a.Ga : mat == 2 ? a.P : a.Gd;

        unsigned short (*As)[40] = (unsigned short (*)[40])lds;               // [32][40]
        unsigned short (*Bs)[40] = (unsigned short (*)[40])(lds + 32 * 40);   // [256][40]

        f32x4 acc[2][4] = {};

        for (int k0 = 0; k0 < 256; k0 += 32) {
            {                                        // A: 32x32 fp32 = 256 float4
                int row = tid >> 3, c4 = tid & 7;
                float4 v = *(const float4*)(Ap + (size_t)(m0 + row) * 256 + k0 + c4 * 4);
                u16x4 p; p[0]=f2bf(v.x); p[1]=f2bf(v.y); p[2]=f2bf(v.z); p[3]=f2bf(v.w);
                *(u16x4*)&As[row][c4 * 4] = p;
            }
            #pragma unroll
            for (int i = 0; i < 8; ++i) {            // W: 256x32 fp32 = 2048 float4
                int idx = tid + i * 256, row = idx >> 3, c4 = idx & 7;
                float4 v = *(const float4*)(Wm + (size_t)row * 256 + k0 + c4 * 4);
                u16x4 p; p[0]=f2bf(v.x); p[1]=f2bf(v.y); p[2]=f2bf(v.z); p[3]=f2bf(v.w);
                *(u16x4*)&Bs[row][c4 * 4] = p;
            }
            __syncthreads();
            bf16x8 af[2], bb[4];
            #pragma unroll
            for (int i = 0; i < 2; ++i) af[i] = ldfrag(&As[i * 16 + ln][q * 8]);
            #pragma unroll
            for (int j = 0; j < 4; ++j) bb[j] = ldfrag(&Bs[w * 64 + j * 16 + ln][q * 8]);
            #pragma unroll
            for (int i = 0; i < 2; ++i)
                #pragma unroll
                for (int j = 0; j < 4; ++j)
                    acc[i][j] = __builtin_amdgcn_mfma_f32_16x16x32_bf16(af[i], bb[j], acc[i][j], 0, 0, 0);
            __syncthreads();
        }

        #pragma unroll
        for (int i = 0; i < 2; ++i)
            #pragma unroll
            for (int j = 0; j < 4; ++j) {
                int n = w * 64 + j * 16 + ln;
                float bias = Bv[n];
                #pragma unroll
                for (int r = 0; r < 4; ++r) {
                    int m = m0 + i * 16 + q * 4 + r;
                    O[(size_t)m * 256 + n] = f2bf(acc[i][j][r] + bias);
                }
            }
    }
    gridbar(a.bar);

    // ===== P2a: TW/PQ GEMM 64x64, K=256 (W from fp32). 1024 jobs ============
    // side = bid>>9, mtile = (bid&511)>>2 (64 rows), ntile = bid&3 (64 cols).
    {
        const int side = bid >> 9, rem = bid & 511, mtile = rem >> 2, ntile = rem & 3;
        const unsigned short* Ap = side ? a.P : a.T;
        const float* Wm = side ? a.Q_w : a.W_w;
        unsigned short* O = side ? a.PQ : a.TW;
        const int m0 = mtile * 64, n0 = ntile * 64;

        unsigned short (*As)[40] = (unsigned short (*)[40])lds;               // [64][40]
        unsigned short (*Bs)[40] = (unsigned short (*)[40])(lds + 64 * 40);   // [64][40]

        f32x4 acc[2][2] = {};

        for (int k0 = 0; k0 < 256; k0 += 32) {
            {                                        // A: 64x32 bf16 = 256 u16x8
                int row = tid >> 2, c8 = tid & 3;
                *(u16x8*)&As[row][c8 * 8] = *(const u16x8*)(Ap + (size_t)(m0 + row) * 256 + k0 + c8 * 8);
            }
            #pragma unroll
            for (int i = 0; i < 2; ++i) {            // W: 64x32 fp32 = 512 float4
                int idx = tid + i * 256, row = idx >> 3, c4 = idx & 7;
                float4 v = *(const float4*)(Wm + (size_t)(n0 + row) * 256 + k0 + c4 * 4);
                u16x4 p; p[0]=f2bf(v.x); p[1]=f2bf(v.y); p[2]=f2bf(v.z); p[3]=f2bf(v.w);
                *(u16x4*)&Bs[row][c4 * 4] = p;
            }
            __syncthreads();
            bf16x8 af[2], bb[2];
            #pragma unroll
            for (int i = 0; i < 2; ++i) af[i] = ldfrag(&As[wr * 32 + i * 16 + ln][q * 8]);
            #pragma unroll
            for (int j = 0; j < 2; ++j) bb[j] = ldfrag(&Bs[wc * 32 + j * 16 + ln][q * 8]);
            #pragma unroll
            for (int i = 0; i < 2; ++i)
                #pragma unroll
                for (int j = 0; j < 2; ++j)
                    acc[i][j] = __builtin_amdgcn_mfma_f32_16x16x32_bf16(af[i], bb[j], acc[i][j], 0, 0, 0);
            __syncthreads();
        }

        #pragma unroll
        for (int i = 0; i < 2; ++i)
            #pragma unroll
            for (int j = 0; j < 2; ++j) {
                int n = n0 + wc * 32 + j * 16 + ln;
                #pragma unroll
                for (int r = 0; r < 4; ++r) {
                    int m = m0 + wr * 32 + i * 16 + q * 4 + r;
                    O[(size_t)m * 256 + n] = f2bf(acc[i][j][r]);
                }
            }
    }

    // ===== P2b: S partials 64(m)x32(n), KC=256 -> atomic into S. 1024 jobs ==
    // which = bid>>9, batch = (bid&511)>>7, mt = (bid>>6)&1, nt = (bid>>4)&3, chunk = bid&15.
    {
        const int which = bid >> 9, rem = bid & 511, batch = rem >> 7, rem2 = rem & 127;
        const int mt = rem2 >> 6, nt = (rem2 >> 4) & 3, chunk = rem2 & 15;
        const unsigned short* Ap = (which ? a.Ga : a.Gd) + (size_t)batch * 524288;
        const unsigned short* Bp = (which ? a.T  : a.P ) + (size_t)batch * 524288;
        float* Sp = a.S + ((size_t)(which * 4 + batch) << 14);
        const int kbeg = chunk * 256, m0 = mt * 64, n0 = nt * 32;

        unsigned short (*As)[72] = (unsigned short (*)[72])lds;               // [64][72]
        unsigned short (*Bs)[72] = (unsigned short (*)[72])(lds + 64 * 72);   // [32][72]

        f32x4 acc[2] = {};

        for (int kk = 0; kk < 4; ++kk) {
            const int k0 = kbeg + kk * 64;
            #pragma unroll
            for (int i = 0; i < 2; ++i) {            // A: 64x64 bf16 = 512 u16x8
                int c = tid + i * 256, row = c >> 3, c8 = c & 7;
                *(u16x8*)&As[row][c8 * 8] = *(const u16x8*)(Ap + (size_t)(m0 + row) * 4096 + k0 + c8 * 8);
            }
            {                                        // B: 32x64 bf16 = 256 u16x8
                int row = tid >> 3, c8 = tid & 7;
                *(u16x8*)&Bs[row][c8 * 8] = *(const u16x8*)(Bp + (size_t)(n0 + row) * 4096 + k0 + c8 * 8);
            }
            __syncthreads();
            #pragma unroll
            for (int ks = 0; ks < 2; ++ks) {
                bf16x8 af, bb[2];
                af = ldfrag(&As[w * 16 + ln][ks * 32 + q * 8]);
                #pragma unroll
                for (int j = 0; j < 2; ++j) bb[j] = ldfrag(&Bs[j * 16 + ln][ks * 32 + q * 8]);
                #pragma unroll
                for (int j = 0; j < 2; ++j)
                    acc[j] = __builtin_amdgcn_mfma_f32_16x16x32_bf16(af, bb[j], acc[j], 0, 0, 0);
            }
            __syncthreads();
        }

        #pragma unroll
        for (int j = 0; j < 2; ++j)
            #pragma unroll
            for (int r = 0; r < 4; ++r) {
                int m = m0 + w * 16 + q * 4 + r, n = n0 + j * 16 + ln;
                unsafeAtomicAdd(Sp + m * 128 + n, acc[j][r]);
            }
    }
    gridbar(a.bar + 1536);

    // ===== P4: combine out = S~ @ TW_q + bias + residual. 1024 jobs =========
    // which = bid>>9, batch=(bid&511)>>7, qq=(rem2>>3), dtile=(rem2>>1)&3, ihalf=rem2&1.
    {
        const int which = bid >> 9, rem = bid & 511, batch = rem >> 7, rem2 = rem & 127;
        const int qq = rem2 >> 3, dtile = (rem2 >> 1) & 3, ihalf = rem2 & 1;
        const int d0 = dtile * 64, i0 = ihalf * 64;
        const float* Sm = a.S + ((size_t)(which * 4 + batch) << 14);
        const unsigned short* Bsrc = (which ? a.PQ : a.TW) + (size_t)batch * 524288;
        const float* Bv = which ? a.b_Q : a.b_W;
        const float* R  = (which ? a.detect : a.aim) + (size_t)batch * 524288;
        float* O = (which ? a.out_det : a.out_aim) + (size_t)batch * 524288;

        unsigned short (*As)[72] = (unsigned short (*)[72])lds;               // [64][72]
        unsigned short (*Bs)[72] = (unsigned short (*)[72])(lds + 64 * 72);   // [64][72]

        f32x4 acc[2][2] = {};

        for (int kk = 0; kk < 2; ++kk) {
            const int k0 = kk * 64;
            #pragma unroll
            for (int i = 0; i < 4; ++i) {            // A: 64x64 fp32, scale+convert
                int idx = tid + i * 256, row = idx >> 4, c4 = idx & 15;
                float4 v = *(const float4*)(Sm + (size_t)(i0 + row) * 128 + k0 + c4 * 4);
                u16x4 p;
                p[0]=f2bf(v.x * (1.0f/4096.0f)); p[1]=f2bf(v.y * (1.0f/4096.0f));
                p[2]=f2bf(v.z * (1.0f/4096.0f)); p[3]=f2bf(v.w * (1.0f/4096.0f));
                *(u16x4*)&As[row][c4 * 4] = p;
            }
            #pragma unroll
            for (int i = 0; i < 2; ++i) {            // B: gather rows 16k+qq, transpose
                int c = tid + i * 256, krow = c >> 3, dc = (c & 7) * 8;
                int gr = 16 * (k0 + krow) + qq;
                u16x8 v = *(const u16x8*)(Bsrc + (size_t)gr * 256 + d0 + dc);
                #pragma unroll
                for (int jj = 0; jj < 8; ++jj) Bs[dc + jj][krow] = v[jj];
            }
            __syncthreads();
            #pragma unroll
            for (int ks = 0; ks < 2; ++ks) {
                bf16x8 af[2], bb[2];
                #pragma unroll
                for (int i = 0; i < 2; ++i) af[i] = ldfrag(&As[wr * 32 + i * 16 + ln][ks * 32 + q * 8]);
                #pragma unroll
                for (int j = 0; j < 2; ++j) bb[j] = ldfrag(&Bs[wc * 32 + j * 16 + ln][ks * 32 + q * 8]);
                #pragma unroll
                for (int i = 0; i < 2; ++i)
                    #pragma unroll
                    for (int j = 0; j < 2; ++j)
                        acc[i][j] = __builtin_amdgcn_mfma_f32_16x16x32_bf16(af[i], bb[j], acc[i][j], 0, 0, 0);
            }
            __syncthreads();
        }

        #pragma unroll
        for (int i = 0; i < 2; ++i)
            #pragma unroll
            for (int j = 0; j < 2; ++j) {
                int d = d0 + wc * 32 + j * 16 + ln;
                float bias = Bv[d];
                #pragma unroll
                for (int r = 0; r < 4; ++r) {
                    int iS = i0 + wr * 32 + i * 16 + q * 4 + r;
                    size_t off = (size_t)(16 * iS + qq) * 256 + d;
                    O[off] = acc[i][j][r] + bias + R[off];
                }
            }
    }
}

extern "C" void kernel_launch(void* const* d_in, const int* in_sizes, int n_in,
                              void* d_out, int out_size, void* d_ws, size_t ws_size,
                              hipStream_t stream)
{
    const size_t TOT = 8192L * 256;   // 2,097,152 elems per tensor

    unsigned short* ws16 = (unsigned short*)d_ws;
    unsigned short* T   = ws16;
    unsigned short* P   = T  + TOT;
    unsigned short* Gd  = P  + TOT;
    unsigned short* Ga  = Gd + TOT;
    unsigned short* TW  = Ga + TOT;             // T @ W^T  bf16 [8192,256]
    unsigned short* PQ  = TW + TOT;             // P @ Q^T  bf16 [8192,256]
    float* S    = (float*)(PQ + TOT);           // [2][4][128][128] fp32 (atomic accum)
    unsigned* bar = (unsigned*)(S + 131072);    // 2 x 1536 uints

    float* out_det = (float*)d_out;
    float* out_aim = out_det + TOT;

    MegaArgs h;
    h.detect = (const float*)d_in[0];
    h.aim    = (const float*)d_in[1];
    h.g_w  = (const float*)d_in[2];  h.b_g  = (const float*)d_in[3];
    h.g2_w = (const float*)d_in[4];  h.b_g2 = (const float*)d_in[5];
    h.th_w = (const float*)d_in[6];  h.b_th = (const float*)d_in[7];
    h.ph_w = (const float*)d_in[8];  h.b_ph = (const float*)d_in[9];
    h.W_w  = (const float*)d_in[10]; h.b_W  = (const float*)d_in[11];
    h.Q_w  = (const float*)d_in[12]; h.b_Q  = (const float*)d_in[13];
    h.T = T; h.P = P; h.Gd = Gd; h.Ga = Ga; h.TW = TW; h.PQ = PQ;
    h.S = S; h.out_aim = out_aim; h.out_det = out_det;
    h.bar = bar;

    // zero S (atomic accumulators) + barrier flags in one capture-legal memset
    hipMemsetAsync(S, 0, 131072 * 4 + 2 * 1536 * 4, stream);
    mega_kernel<<<dim3(1024), dim3(256), 0, stream>>>(h);
}

// Round 7
// 145.364 us; speedup vs baseline: 1.6557x; 1.6557x over previous
//
#include <hip/hip_runtime.h>

// B=4, N=2048, C=256, ic=128.  Algebra (validated rounds 1-9):
//   T=lin(aim,theta) P=lin(detect,phi) Gd=lin(detect,g) Ga=lin(aim,g2)   [bf16]
//   X_v := per-batch view [128,4096] of [2048,256] (pure reshape)
//   S_aT = Gd_v @ P_v^T ; S_bT = Ga_v @ T_v^T        [128,128] fp32
//   out_aim[r,d] = (1/4096)*sum_k S_aT[r/16,k]*TW[16k+(r%16),d] + Wb[d] + aim[r,d]
//   with TW = T @ W^T  (and symmetrically out_det from S_bT, PQ = P @ Q^T).
// Round 10: back to MULTI-KERNEL (graph replay makes launch boundaries ~free;
//   all barrier-fused megas lost: 120-152 us vs ~60 us as separate kernels).
//   Keep only the validated phase eliminations from the mega experiments:
//   - K1 lin4 stages fp32 inputs with inline convert (prep kernel GONE)
//   - K2 twpq + s_part, partials unsafeAtomicAdd'ed into S (sred GONE,
//     17 MB Spart round trip -> 0.5 MB; S zeroed by capture-legal memset)
//   - K3 combine stages S fp32 with inline scale+convert
//   6 kernels -> 3 (+512KB memset), no barriers, no cooperative launch.

typedef __attribute__((ext_vector_type(4))) float  f32x4;
typedef __attribute__((ext_vector_type(8))) __bf16 bf16x8;
typedef __attribute__((ext_vector_type(8))) unsigned short u16x8;
typedef __attribute__((ext_vector_type(4))) unsigned short u16x4;

__device__ inline unsigned short f2bf(float f) {
    union { float f; unsigned u; } c; c.f = f;
    unsigned r = c.u + 0x7FFF + ((c.u >> 16) & 1);   // RNE
    return (unsigned short)(r >> 16);
}
__device__ inline bf16x8 ldfrag(const unsigned short* p) {
    return __builtin_bit_cast(bf16x8, *(const u16x8*)p);
}

// ---------------- K1: four input linears (fp32 in, inline convert) -----------
// grid (512): z = bid>>8 (0:aim,1:detect), set = bid&1, mtile = (bid&255)>>1.
// Tile 64x256, BK=32.  (= round-5 mega P1, verified)
__global__ __launch_bounds__(256)
void lin4_kernel(const float* __restrict__ aim, const float* __restrict__ detect,
                 const float* __restrict__ g_w, const float* __restrict__ g2_w,
                 const float* __restrict__ th_w, const float* __restrict__ ph_w,
                 const float* __restrict__ b_g, const float* __restrict__ b_g2,
                 const float* __restrict__ b_th, const float* __restrict__ b_ph,
                 unsigned short* __restrict__ T,  unsigned short* __restrict__ Ga,
                 unsigned short* __restrict__ P,  unsigned short* __restrict__ Gd)
{
    const int bid = blockIdx.x, tid = threadIdx.x;
    const int lane = tid & 63, w = tid >> 6;
    const int wr = w >> 1, wc = w & 1, q = lane >> 4, ln = lane & 15;

    const int z = bid >> 8, rem = bid & 255, set = rem & 1, mtile = rem >> 1;
    const float* Ap = z ? detect : aim;
    const float* Wm = z ? (set ? g_w : ph_w) : (set ? g2_w : th_w);
    const float* Bv = z ? (set ? b_g : b_ph) : (set ? b_g2 : b_th);
    unsigned short* O = z ? (set ? Gd : P) : (set ? Ga : T);
    const int m0 = mtile * 64;

    __shared__ unsigned short As[64][40];    // [m][k] bf16
    __shared__ unsigned short Bs[256][40];   // [n][k]

    f32x4 acc[2][8] = {};

    for (int k0 = 0; k0 < 256; k0 += 32) {
        #pragma unroll
        for (int i = 0; i < 2; ++i) {            // A: 64x32 fp32 = 512 float4
            int idx = tid + i * 256, row = idx >> 3, c4 = idx & 7;
            float4 v = *(const float4*)(Ap + (size_t)(m0 + row) * 256 + k0 + c4 * 4);
            u16x4 p; p[0]=f2bf(v.x); p[1]=f2bf(v.y); p[2]=f2bf(v.z); p[3]=f2bf(v.w);
            *(u16x4*)&As[row][c4 * 4] = p;
        }
        #pragma unroll
        for (int i = 0; i < 8; ++i) {            // W: 256x32 fp32 = 2048 float4
            int idx = tid + i * 256, row = idx >> 3, c4 = idx & 7;
            float4 v = *(const float4*)(Wm + (size_t)row * 256 + k0 + c4 * 4);
            u16x4 p; p[0]=f2bf(v.x); p[1]=f2bf(v.y); p[2]=f2bf(v.z); p[3]=f2bf(v.w);
            *(u16x4*)&Bs[row][c4 * 4] = p;
        }
        __syncthreads();
        bf16x8 af[2], bb[8];
        #pragma unroll
        for (int i = 0; i < 2; ++i) af[i] = ldfrag(&As[wr * 32 + i * 16 + ln][q * 8]);
        #pragma unroll
        for (int j = 0; j < 8; ++j) bb[j] = ldfrag(&Bs[wc * 128 + j * 16 + ln][q * 8]);
        #pragma unroll
        for (int i = 0; i < 2; ++i)
            #pragma unroll
            for (int j = 0; j < 8; ++j)
                acc[i][j] = __builtin_amdgcn_mfma_f32_16x16x32_bf16(af[i], bb[j], acc[i][j], 0, 0, 0);
        __syncthreads();
    }

    #pragma unroll
    for (int i = 0; i < 2; ++i)
        #pragma unroll
        for (int j = 0; j < 8; ++j) {
            int n = wc * 128 + j * 16 + ln;
            float bias = Bv[n];
            #pragma unroll
            for (int r = 0; r < 4; ++r) {
                int m = m0 + wr * 32 + i * 16 + q * 4 + r;
                O[(size_t)m * 256 + n] = f2bf(acc[i][j][r] + bias);
            }
        }
}

// ---------------- K2: TW/PQ GEMMs + S partials (atomic) ----------------------
// grid (1024): bx<512 -> twpq (side, mtile(128), nhalf; tile 64x128, W fp32);
//              bx>=512 -> s_part (which, batch, mt, nt, chunk(16); tile 64x64,
//              KC=256, unsafeAtomicAdd into S).  (= round-5 mega P2a/P2b)
__global__ __launch_bounds__(256)
void mid_kernel(const unsigned short* __restrict__ T, const unsigned short* __restrict__ P,
                const unsigned short* __restrict__ Gd, const unsigned short* __restrict__ Ga,
                const float* __restrict__ W_w, const float* __restrict__ Q_w,
                unsigned short* __restrict__ TW, unsigned short* __restrict__ PQ,
                float* __restrict__ S)
{
    __shared__ unsigned short lds[9216];     // 18432 B: max(twpq 15360, s_part 18432)

    const int tid = threadIdx.x, lane = tid & 63, w = tid >> 6;
    const int wr = w >> 1, wc = w & 1, q = lane >> 4, ln = lane & 15;

    if (blockIdx.x < 512) {
        // ------------------ twpq: 64x128, K=256, W from fp32 ------------------
        const int bid = blockIdx.x;
        const int side = bid >> 8, rem = bid & 255, mtile = rem >> 1, nhalf = rem & 1;
        const unsigned short* Ap = side ? P : T;
        const float* Wm = side ? Q_w : W_w;
        unsigned short* O = side ? PQ : TW;
        const int m0 = mtile * 64, n0 = nhalf * 128;

        unsigned short (*As)[40] = (unsigned short (*)[40])lds;               // [64][40]
        unsigned short (*Bs)[40] = (unsigned short (*)[40])(lds + 64 * 40);   // [128][40]

        f32x4 acc[2][4] = {};

        for (int k0 = 0; k0 < 256; k0 += 32) {
            {                                        // A: 64x32 bf16 = 256 u16x8
                int row = tid >> 2, c8 = tid & 3;
                *(u16x8*)&As[row][c8 * 8] = *(const u16x8*)(Ap + (size_t)(m0 + row) * 256 + k0 + c8 * 8);
            }
            #pragma unroll
            for (int i = 0; i < 4; ++i) {            // W: 128x32 fp32 = 1024 float4
                int idx = tid + i * 256, row = idx >> 3, c4 = idx & 7;
                float4 v = *(const float4*)(Wm + (size_t)(n0 + row) * 256 + k0 + c4 * 4);
                u16x4 p; p[0]=f2bf(v.x); p[1]=f2bf(v.y); p[2]=f2bf(v.z); p[3]=f2bf(v.w);
                *(u16x4*)&Bs[row][c4 * 4] = p;
            }
            __syncthreads();
            bf16x8 af[2], bb[4];
            #pragma unroll
            for (int i = 0; i < 2; ++i) af[i] = ldfrag(&As[wr * 32 + i * 16 + ln][q * 8]);
            #pragma unroll
            for (int j = 0; j < 4; ++j) bb[j] = ldfrag(&Bs[wc * 64 + j * 16 + ln][q * 8]);
            #pragma unroll
            for (int i = 0; i < 2; ++i)
                #pragma unroll
                for (int j = 0; j < 4; ++j)
                    acc[i][j] = __builtin_amdgcn_mfma_f32_16x16x32_bf16(af[i], bb[j], acc[i][j], 0, 0, 0);
            __syncthreads();
        }

        #pragma unroll
        for (int i = 0; i < 2; ++i)
            #pragma unroll
            for (int j = 0; j < 4; ++j) {
                int n = n0 + wc * 64 + j * 16 + ln;
                #pragma unroll
                for (int r = 0; r < 4; ++r) {
                    int m = m0 + wr * 32 + i * 16 + q * 4 + r;
                    O[(size_t)m * 256 + n] = f2bf(acc[i][j][r]);
                }
            }
    } else {
        // ------------------ s_part: 64x64, KC=256, atomic into S --------------
        const int bid = blockIdx.x - 512;
        const int which = bid >> 8, rem = bid & 255, batch = rem >> 6, rem2 = rem & 63;
        const int mt = rem2 >> 5, nt = (rem2 >> 4) & 1, chunk = rem2 & 15;
        const unsigned short* Ap = (which ? Ga : Gd) + (size_t)batch * 524288;
        const unsigned short* Bp = (which ? T  : P ) + (size_t)batch * 524288;
        float* Sp = S + ((size_t)(which * 4 + batch) << 14);
        const int kbeg = chunk * 256, m0 = mt * 64, n0 = nt * 64;

        unsigned short (*As)[72] = (unsigned short (*)[72])lds;               // [64][72]
        unsigned short (*Bs)[72] = (unsigned short (*)[72])(lds + 64 * 72);   // [64][72]

        f32x4 acc[2][2] = {};

        for (int kk = 0; kk < 4; ++kk) {
            const int k0 = kbeg + kk * 64;
            #pragma unroll
            for (int i = 0; i < 2; ++i) {            // A,B: 64x64 bf16 = 512 u16x8 each
                int c = tid + i * 256, row = c >> 3, c8 = c & 7;
                *(u16x8*)&As[row][c8 * 8] = *(const u16x8*)(Ap + (size_t)(m0 + row) * 4096 + k0 + c8 * 8);
                *(u16x8*)&Bs[row][c8 * 8] = *(const u16x8*)(Bp + (size_t)(n0 + row) * 4096 + k0 + c8 * 8);
            }
            __syncthreads();
            #pragma unroll
            for (int ks = 0; ks < 2; ++ks) {
                bf16x8 af[2], bb[2];
                #pragma unroll
                for (int i = 0; i < 2; ++i) af[i] = ldfrag(&As[wr * 32 + i * 16 + ln][ks * 32 + q * 8]);
                #pragma unroll
                for (int j = 0; j < 2; ++j) bb[j] = ldfrag(&Bs[wc * 32 + j * 16 + ln][ks * 32 + q * 8]);
                #pragma unroll
                for (int i = 0; i < 2; ++i)
                    #pragma unroll
                    for (int j = 0; j < 2; ++j)
                        acc[i][j] = __builtin_amdgcn_mfma_f32_16x16x32_bf16(af[i], bb[j], acc[i][j], 0, 0, 0);
            }
            __syncthreads();
        }

        #pragma unroll
        for (int i = 0; i < 2; ++i)
            #pragma unroll
            for (int j = 0; j < 2; ++j)
                #pragma unroll
                for (int r = 0; r < 4; ++r) {
                    int m = m0 + wr * 32 + i * 16 + q * 4 + r, n = n0 + wc * 32 + j * 16 + ln;
                    unsafeAtomicAdd(Sp + m * 128 + n, acc[i][j][r]);   // HW global_atomic_add_f32
                }
    }
}

// ---------------- K3: combine  out = S~ @ TW_q + bias + residual -------------
// grid (512): which=bid>>8, batch=(bid>>6)&3, qq=(bid>>2)&15, dtile=(bid>>1)&1,
// ihalf=bid&1. Tile 64(i) x 128(d), K=128; S staged fp32 with scale+convert.
// (= round-5 mega P4, verified)
__global__ __launch_bounds__(256)
void combine_kernel(const float* __restrict__ S,
                    const unsigned short* __restrict__ TW, const unsigned short* __restrict__ PQ,
                    const float* __restrict__ W_b, const float* __restrict__ Q_b,
                    const float* __restrict__ aim, const float* __restrict__ detect,
                    float* __restrict__ out_aim, float* __restrict__ out_det)
{
    const int bid = blockIdx.x, tid = threadIdx.x;
    const int lane = tid & 63, w = tid >> 6;
    const int wr = w >> 1, wc = w & 1, q = lane >> 4, ln = lane & 15;

    const int which = bid >> 8, batch = (bid >> 6) & 3, qq = (bid >> 2) & 15;
    const int dtile = (bid >> 1) & 1, ihalf = bid & 1;
    const int d0 = dtile * 128, i0 = ihalf * 64;
    const float* Sm = S + ((size_t)(which * 4 + batch) << 14);
    const unsigned short* Bsrc = (which ? PQ : TW) + (size_t)batch * 524288;
    const float* Bv = which ? Q_b : W_b;
    const float* R  = (which ? detect : aim) + (size_t)batch * 524288;
    float* O = (which ? out_det : out_aim) + (size_t)batch * 524288;

    __shared__ unsigned short As[64][72];    // S~ [i][k] bf16 (scaled)
    __shared__ unsigned short Bs[128][72];   // TW_q^T [d][k]

    f32x4 acc[2][4] = {};

    for (int kk = 0; kk < 2; ++kk) {
        const int k0 = kk * 64;
        #pragma unroll
        for (int i = 0; i < 4; ++i) {            // A: 64x64 fp32, scale+convert
            int idx = tid + i * 256, row = idx >> 4, c4 = idx & 15;
            float4 v = *(const float4*)(Sm + (size_t)(i0 + row) * 128 + k0 + c4 * 4);
            u16x4 p;
            p[0]=f2bf(v.x * (1.0f/4096.0f)); p[1]=f2bf(v.y * (1.0f/4096.0f));
            p[2]=f2bf(v.z * (1.0f/4096.0f)); p[3]=f2bf(v.w * (1.0f/4096.0f));
            *(u16x4*)&As[row][c4 * 4] = p;
        }
        #pragma unroll
        for (int i = 0; i < 4; ++i) {            // B: gather 64 rows 16k+qq, transpose
            int c = tid + i * 256, krow = c >> 4, dc = (c & 15) * 8;
            int gr = 16 * (k0 + krow) + qq;
            u16x8 v = *(const u16x8*)(Bsrc + (size_t)gr * 256 + d0 + dc);
            #pragma unroll
            for (int jj = 0; jj < 8; ++jj) Bs[dc + jj][krow] = v[jj];
        }
        __syncthreads();
        #pragma unroll
        for (int ks = 0; ks < 2; ++ks) {
            bf16x8 af[2], bb[4];
            #pragma unroll
            for (int i = 0; i < 2; ++i) af[i] = ldfrag(&As[wr * 32 + i * 16 + ln][ks * 32 + q * 8]);
            #pragma unroll
            for (int j = 0; j < 4; ++j) bb[j] = ldfrag(&Bs[wc * 64 + j * 16 + ln][ks * 32 + q * 8]);
            #pragma unroll
            for (int i = 0; i < 2; ++i)
                #pragma unroll
                for (int j = 0; j < 4; ++j)
                    acc[i][j] = __builtin_amdgcn_mfma_f32_16x16x32_bf16(af[i], bb[j], acc[i][j], 0, 0, 0);
        }
        __syncthreads();
    }

    #pragma unroll
    for (int i = 0; i < 2; ++i)
        #pragma unroll
        for (int j = 0; j < 4; ++j) {
            int d = d0 + wc * 64 + j * 16 + ln;
            float bias = Bv[d];
            #pragma unroll
            for (int r = 0; r < 4; ++r) {
                int iS = i0 + wr * 32 + i * 16 + q * 4 + r;
                size_t off = (size_t)(16 * iS + qq) * 256 + d;
                O[off] = acc[i][j][r] + bias + R[off];
            }
        }
}

extern "C" void kernel_launch(void* const* d_in, const int* in_sizes, int n_in,
                              void* d_out, int out_size, void* d_ws, size_t ws_size,
                              hipStream_t stream)
{
    const float* detect = (const float*)d_in[0];
    const float* aim    = (const float*)d_in[1];
    const float* g_w  = (const float*)d_in[2];  const float* g_b  = (const float*)d_in[3];
    const float* g2_w = (const float*)d_in[4];  const float* g2_b = (const float*)d_in[5];
    const float* th_w = (const float*)d_in[6];  const float* th_b = (const float*)d_in[7];
    const float* ph_w = (const float*)d_in[8];  const float* ph_b = (const float*)d_in[9];
    const float* W_w  = (const float*)d_in[10]; const float* W_b  = (const float*)d_in[11];
    const float* Q_w  = (const float*)d_in[12]; const float* Q_b  = (const float*)d_in[13];

    const size_t TOT = 8192L * 256;   // 2,097,152 elems per tensor

    unsigned short* ws16 = (unsigned short*)d_ws;
    unsigned short* T   = ws16;
    unsigned short* P   = T  + TOT;
    unsigned short* Gd  = P  + TOT;
    unsigned short* Ga  = Gd + TOT;
    unsigned short* TW  = Ga + TOT;             // T @ W^T  bf16 [8192,256]
    unsigned short* PQ  = TW + TOT;             // P @ Q^T  bf16 [8192,256]
    float* S    = (float*)(PQ + TOT);           // [2][4][128][128] fp32 (atomic accum)

    float* out_det = (float*)d_out;
    float* out_aim = out_det + TOT;

    hipMemsetAsync(S, 0, 131072 * 4, stream);   // zero atomic accumulators
    lin4_kernel<<<dim3(512), 256, 0, stream>>>(
        aim, detect, g_w, g2_w, th_w, ph_w, g_b, g2_b, th_b, ph_b, T, Ga, P, Gd);
    mid_kernel<<<dim3(1024), 256, 0, stream>>>(T, P, Gd, Ga, W_w, Q_w, TW, PQ, S);
    combine_kernel<<<dim3(512), 256, 0, stream>>>(
        S, TW, PQ, W_b, Q_b, aim, detect, out_aim, out_det);
}